// Round 10
// baseline (118.513 us; speedup 1.0000x reference)
//
#include <hip/hip_runtime.h>
#include <type_traits>

// DCNv2 forward, MI355X (gfx950).  v12-retry: two independent barrier groups
// per CU. RESUBMIT of round-9 source (byte-identical kernel logic): the
// round-9 bench died with a container-infra error, and a full static audit
// (uniform 19-barrier counts both roles, all bounds closed, swizzle
// write/read XOR consistent, all slot indices compile-time, no spin-waits)
// found no hang/fault mechanism. One retry before convicting the design.
//  v8->v9 measured lockstep-barrier convergence at ~840 cyc/event with 16
//  waves / 1 block per CU. v12 splits the verified v9 gemm into 2 blocks/CU:
//  512 thr, 32x256 tile, grid 512. 4 consumer waves (32r x 64oc: acc[2][4],
//  bfr[2][8]) + 4 producer waves. Identical phase protocol / slot rotation /
//  swizzles as v9; only index widths change. When one block converges at its
//  barrier, the other block's waves issue.
//  k_pre unchanged; k_offconv = v11 single-barrier double-buffer (verified).
//  wmain stays in MFMA B-fragment order:
//  wmain[(k>>5)*8192 + (oc>>4)*512 + ((k>>3)&3)*128 + (oc&15)*8 + (k&7)]

typedef __bf16 bf16x8 __attribute__((ext_vector_type(8)));
typedef float  f32x4  __attribute__((ext_vector_type(4)));
typedef unsigned short ushort8 __attribute__((ext_vector_type(8)));
typedef unsigned int   uint4v  __attribute__((ext_vector_type(4)));

#define XBF_OFF   0u            // 4*4096*256*2  = 8,388,608
#define WREP_OFF  8388608u      // 32*2304*2     =   147,456
#define WMAIN_OFF 8536064u      // 256*2304*2    = 1,179,648
#define OM_OFF    9715712u      // 16384*32*4    = 2,097,152

// wait lgkmcnt(0) only (vmcnt=no wait), then barrier.
#define LGKM0_BAR() do { __builtin_amdgcn_s_waitcnt(0xC07F); __builtin_amdgcn_s_barrier(); } while (0)

template <int N> using ic = std::integral_constant<int, N>;

__device__ __forceinline__ unsigned short f2bf(float f) {
  unsigned int u = __float_as_uint(f);
  u += 0x7fffu + ((u >> 16) & 1u);
  return (unsigned short)(u >> 16);
}
__device__ __forceinline__ float bf2f(unsigned short h) {
  return __uint_as_float(((unsigned int)h) << 16);
}

// ---------------- merged transpose + weight repack ----------------
__global__ __launch_bounds__(256) void k_pre(const float* __restrict__ x,
                                             const float* __restrict__ w_off,
                                             const float* __restrict__ dcn_w,
                                             unsigned short* __restrict__ xbf,
                                             unsigned short* __restrict__ wrep,
                                             unsigned short* __restrict__ wmain) {
  __shared__ float tile[32][65];
  __shared__ unsigned short lsh[2304];
  int b = blockIdx.x;
  int t = threadIdx.x;
  if (b < 2048) {               // transpose role
    int n  = b >> 9;
    int cb = (b >> 6) & 7;
    int xb = b & 63;
    int xx  = t & 63;
    int cc0 = t >> 6;
#pragma unroll
    for (int j = 0; j < 8; ++j) {
      int cc = cc0 + j * 4;
      tile[cc][xx] = x[((size_t)(n * 256 + cb * 32 + cc) << 12) + xb * 64 + xx];
    }
    __syncthreads();
    int ccw = t & 31;
    int xw0 = t >> 5;
#pragma unroll
    for (int j = 0; j < 8; ++j) {
      int xw = xw0 + j * 8;
      xbf[((size_t)((n << 12) + xb * 64 + xw)) * 256 + cb * 32 + ccw] = f2bf(tile[ccw][xw]);
    }
  } else {                      // repack role: one block per output channel
    int ocb = b - 2048;
    if (ocb < 32) {             // offset-conv weights: layout unchanged
      int oc = ocb;
      if (oc >= 27) {
#pragma unroll
        for (int j = 0; j < 9; ++j) wrep[oc * 2304 + j * 256 + t] = 0;
        return;
      }
      const float* base = w_off + (size_t)oc * 2304;
#pragma unroll
      for (int j = 0; j < 9; ++j) lsh[j * 256 + t] = f2bf(base[t * 9 + j]);
      __syncthreads();
#pragma unroll
      for (int j = 0; j < 9; ++j) wrep[oc * 2304 + j * 256 + t] = lsh[j * 256 + t];
    } else {                    // main weights: MFMA B-fragment order
      int oc = ocb - 32;
      const float* base = dcn_w + (size_t)oc * 2304;
      int oco = ((oc >> 4) << 9) + (oc & 15) * 8;
#pragma unroll
      for (int j = 0; j < 9; ++j) {
        int k = j * 256 + t;    // logical K index: tap-major, channel-minor
        wmain[((k >> 5) << 13) + oco + (((k >> 3) & 3) << 7) + (k & 7)] =
            f2bf(base[t * 9 + j]);
      }
    }
  }
}

// ---------------- offset-field conv: K-split-4, double-buffered, 1 bar/step --
__global__ __launch_bounds__(1024) void k_offconv(const unsigned short* __restrict__ xbf,
                                                  const unsigned short* __restrict__ wrep,
                                                  const float* __restrict__ bias,
                                                  float* __restrict__ om) {
  __shared__ __align__(16) unsigned short SHa[4][2][64 * 64];   // 64 KB
  __shared__ __align__(16) unsigned short SHb[4][2][32 * 64];   // 32 KB
  int t = threadIdx.x;
  int wave = t >> 6, lane = t & 63;
  int grp = wave >> 2, wv = wave & 3;
  int tg = t & 255;
  int bm = ((blockIdx.x & 7) << 5) + (blockIdx.x >> 3);   // XCD swizzle
  int n = bm >> 6, oy = bm & 63;

  unsigned short (*As)[64 * 64] = SHa[grp];
  unsigned short (*Bs)[32 * 64] = SHb[grp];

  int arow = tg >> 2, acc4 = tg & 3;
  int brow = tg >> 3, bch = tg & 7;

  f32x4 acc0 = {0.f, 0.f, 0.f, 0.f};
  f32x4 acc1 = {0.f, 0.f, 0.f, 0.f};

  ushort8 av[2][2]; ushort8 bv[2];
  auto prefetch = [&](int ktg, auto slotc) {
    constexpr int slot = decltype(slotc)::value;
    int kk = ktg >> 2;
    int c0 = (ktg & 3) * 64;
    int dy = kk / 3 - 1, dx = kk % 3 - 1;
    int yy = oy + dy, xxg = arow + dx;
    bool ok = ((unsigned)yy < 64u) && ((unsigned)xxg < 64u);
    const unsigned short* p = xbf + (size_t)(((n * 64 + yy) * 64 + xxg) * 256 + c0 + acc4 * 16);
#pragma unroll
    for (int g = 0; g < 2; ++g)
      av[slot][g] = ok ? *(const ushort8*)(p + g * 8) : (ushort8){0,0,0,0,0,0,0,0};
    bv[slot] = *(const ushort8*)(wrep + (size_t)brow * 2304 + ktg * 64 + bch * 8);
  };

  int k0 = grp * 9;
  prefetch(k0, ic<0>{});
  prefetch(k0 + 1, ic<1>{});
  int mr = lane & 15, q = lane >> 4;

  // step kt: write LDS buf kt&1, prefetch kt+2, ONE barrier, MFMA from buf kt&1.
  auto step = [&](int kt, auto slotc) {
    constexpr int slot = decltype(slotc)::value;
#pragma unroll
    for (int g = 0; g < 2; ++g) {
      int ch = (acc4 * 2 + g) ^ (arow & 7);
      *(ushort8*)&As[slot][arow * 64 + ch * 8] = av[slot][g];
    }
    { int ch = bch ^ (brow & 7);
      *(ushort8*)&Bs[slot][brow * 64 + ch * 8] = bv[slot]; }
    if (kt + 2 < 9) prefetch(k0 + kt + 2, slotc);
    LGKM0_BAR();
#pragma unroll
    for (int kh = 0; kh < 2; ++kh) {
      int coff = ((q + kh * 4) ^ (mr & 7)) * 8;
      bf16x8 a  = *(const bf16x8*)&As[slot][(wv * 16 + mr) * 64 + coff];
      bf16x8 b0 = *(const bf16x8*)&Bs[slot][mr * 64 + coff];
      bf16x8 b1 = *(const bf16x8*)&Bs[slot][(16 + mr) * 64 + coff];
      acc0 = __builtin_amdgcn_mfma_f32_16x16x32_bf16(a, b0, acc0, 0, 0, 0);
      acc1 = __builtin_amdgcn_mfma_f32_16x16x32_bf16(a, b1, acc1, 0, 0, 0);
    }
  };
  for (int kp = 0; kp < 4; ++kp) {
    step(2 * kp, ic<0>{});
    step(2 * kp + 1, ic<1>{});
  }
  step(8, ic<0>{});

  float* scratch = (float*)&SHa[0][0][0];
  __syncthreads();
  if (grp > 0) {
#pragma unroll
    for (int nt = 0; nt < 2; ++nt) {
      f32x4 a = nt ? acc1 : acc0;
#pragma unroll
      for (int rg = 0; rg < 4; ++rg)
        scratch[(grp - 1) * 2048 + (wv * 16 + q * 4 + rg) * 32 + nt * 16 + mr] = a[rg];
    }
  }
  __syncthreads();
  if (grp == 0) {
    int r0 = bm * 64;
#pragma unroll
    for (int nt = 0; nt < 2; ++nt) {
      f32x4 a = nt ? acc1 : acc0;
      int oc = nt * 16 + mr;
      float bvl = (oc < 27) ? bias[oc] : 0.f;
#pragma unroll
      for (int rg = 0; rg < 4; ++rg) {
        int pl = wv * 16 + q * 4 + rg;
        float v = a[rg] + bvl + scratch[pl * 32 + oc] +
                  scratch[2048 + pl * 32 + oc] + scratch[4096 + pl * 32 + oc];
        if (oc >= 18 && oc < 27) v = 1.f / (1.f + __expf(-v));
        om[(r0 + pl) * 32 + oc] = v;
      }
    }
  }
}

// ---------------- fused deformable-im2col GEMM v12 ---------------------------
// v9 protocol halved: 512 thr (4 cons + 4 prod waves), 32x256 tile, grid 512
// = 2 independent barrier groups per CU. BK=128 phases, 19 barriers.
// LDS: Ab[2][32*128] = 16 KB per block.
__global__ __launch_bounds__(512, 4) void k_gemm_fused(const unsigned short* __restrict__ xbf,
                                                       const float* __restrict__ om,
                                                       const unsigned short* __restrict__ wB,
                                                       float* __restrict__ out) {
  __shared__ __align__(16) unsigned short Ab[2][32 * 128];   // 16 KB
  int t = threadIdx.x;
  int wave = t >> 6, lane = t & 63;
  int bmx = ((blockIdx.x & 7) << 6) + (blockIdx.x >> 3);     // XCD swizzle (512)
  int r0 = bmx * 32;

  if (wave < 4) {
    // ============ consumers: waves 0..3, 32 rows x 64 oc each ===============
    int mr = lane & 15, q = lane >> 4;
    const unsigned short* Bg = wB + wave * 2048 + lane * 8;  // oc blk = wave*64
    f32x4 acc[2][4];
#pragma unroll
    for (int mt = 0; mt < 2; ++mt)
#pragma unroll
      for (int nt = 0; nt < 4; ++nt) acc[mt][nt] = (f32x4){0.f, 0.f, 0.f, 0.f};

    bf16x8 bfr[2][8];            // [slot = ks&1][kh*4+nt], ks = 64-K sub-step

    auto issueB = [&](int ks, auto slotc) {      // B(ks) -> slot
      constexpr int slot = decltype(slotc)::value;
#pragma unroll
      for (int kh = 0; kh < 2; ++kh)
#pragma unroll
        for (int nt = 0; nt < 4; ++nt)
          bfr[slot][kh * 4 + nt] =
              *(const bf16x8*)(Bg + (size_t)(ks * 2 + kh) * 8192 + nt * 512);
    };
    // MFMA for sub-step ks: half = ks&1 == B slot (compile-time), buf = (ks>>1)&1
    auto mfma64 = [&](auto halfc, auto bufc) {
      constexpr int half = decltype(halfc)::value;
      constexpr int buf  = decltype(bufc)::value;
      __builtin_amdgcn_s_setprio(1);
#pragma unroll
      for (int kh = 0; kh < 2; ++kh) {
        int coff = half * 64 + ((q + kh * 4) ^ (mr & 7)) * 8;
        bf16x8 af[2];
#pragma unroll
        for (int mt = 0; mt < 2; ++mt)
          af[mt] = *(const bf16x8*)&Ab[buf][(mt * 16 + mr) * 128 + coff];
#pragma unroll
        for (int mt = 0; mt < 2; ++mt)
#pragma unroll
          for (int nt = 0; nt < 4; ++nt)
            acc[mt][nt] = __builtin_amdgcn_mfma_f32_16x16x32_bf16(
                af[mt], bfr[half][kh * 4 + nt], acc[mt][nt], 0, 0, 0);
      }
      __builtin_amdgcn_s_setprio(0);
    };

    // prologue: phase 0 (producers fill buf0); issue B(0).
    issueB(0, ic<0>{});
    LGKM0_BAR();
    // phases p = 1..18: consume buf (p-1)&1 (sub-steps 2p-2, 2p-1)
    auto cphase = [&](int p, auto bufc) {
      issueB(2 * p - 1, ic<1>{});            // used this phase, 2nd sub
      mfma64(ic<0>{}, bufc);                 // MFMA(2p-2): half0, slot0
      if (2 * p < 36) issueB(2 * p, ic<0>{}); // for next phase's 1st sub
      mfma64(ic<1>{}, bufc);                 // MFMA(2p-1): half1, slot1
      LGKM0_BAR();                           // lgkm-only: B loads stay in flight
    };
    for (int pp = 0; pp < 9; ++pp) {
      cphase(2 * pp + 1, ic<0>{});
      cphase(2 * pp + 2, ic<1>{});
    }

    // epilogue: direct stores
#pragma unroll
    for (int mt = 0; mt < 2; ++mt)
#pragma unroll
      for (int nt = 0; nt < 4; ++nt) {
        int p = r0 + mt * 16 + q * 4;
        int o = wave * 64 + nt * 16 + mr;
        int nn = p >> 12, pyx = p & 4095;
        *(f32x4*)(out + ((size_t)(nn * 256 + o) << 12) + pyx) = acc[mt][nt];
      }
  } else {
    // ============ producers: waves 4..7 (A only) ============================
    int pt = t - 256;                    // 0..255
    int srow = pt >> 3, sch = (pt & 7) * 8;   // 32 rows x 8 ch-chunks of 8
    int r = r0 + srow;
    int n = r >> 12, yx = r & 4095, oy = yx >> 6, ox = yx & 63;
    const unsigned short* xb = xbf + (size_t)n * (4096 * 256);
    const float* omr = om + (size_t)r * 32;
    int wchA = (((pt & 7) ^ (srow & 7)) << 3);

    float pv_y, pv_x, pv_m;
    float cw1, cw2, cw3, cw4;
    int a1, a2, a3, a4;
    float wbuf[2][4];
    ushort8 g1[2], g2[2], g3[2], g4[2];

    auto loadom = [&](int kk) {
      pv_y = omr[2 * kk]; pv_x = omr[2 * kk + 1]; pv_m = omr[18 + kk];
    };
    auto params = [&](int kk) {
      float py = (float)(oy + kk / 3) + pv_y;
      float px = (float)(ox + kk % 3) + pv_x;
      float m = pv_m;
      py = fminf(fmaxf(py, 0.f), 65.f);
      px = fminf(fmaxf(px, 0.f), 65.f);
      float fy = floorf(py), fx = floorf(px);
      float ly = py - fy, lx = px - fx;
      float hy = 1.f - ly, hx = 1.f - lx;
      int iy = (int)fy, ix = (int)fx;
      bool yv0 = (iy >= 1) && (iy <= 64);
      bool yv1 = (iy <= 63);
      bool xv0 = (ix >= 1) && (ix <= 64);
      bool xv1 = (ix <= 63);
      int y0 = min(max(iy - 1, 0), 63);
      int y1 = min(iy, 63);
      int x0 = min(max(ix - 1, 0), 63);
      int x1 = min(ix, 63);
      cw1 = (yv0 && xv0) ? hy * hx * m : 0.f;
      cw2 = (yv0 && xv1) ? hy * lx * m : 0.f;
      cw3 = (yv1 && xv0) ? ly * hx * m : 0.f;
      cw4 = (yv1 && xv1) ? ly * lx * m : 0.f;
      a1 = ((y0 << 6) + x0) * 256;
      a2 = ((y0 << 6) + x1) * 256;
      a3 = ((y1 << 6) + x0) * 256;
      a4 = ((y1 << 6) + x1) * 256;
    };

    auto issueA = [&](int ktg, auto slotc) {
      constexpr int slot = decltype(slotc)::value;
      wbuf[slot][0] = cw1; wbuf[slot][1] = cw2; wbuf[slot][2] = cw3; wbuf[slot][3] = cw4;
      int c = (ktg & 3) * 64 + sch;
      g1[slot] = *(const ushort8*)(xb + a1 + c);
      g2[slot] = *(const ushort8*)(xb + a2 + c);
      g3[slot] = *(const ushort8*)(xb + a3 + c);
      g4[slot] = *(const ushort8*)(xb + a4 + c);
    };
    // blend sub-step from slot, write half of buf
    auto blend = [&](auto slotc, auto halfc, auto bufc) {
      constexpr int slot = decltype(slotc)::value;
      constexpr int half = decltype(halfc)::value;
      constexpr int buf  = decltype(bufc)::value;
      uint4v rs;
#pragma unroll
      for (int pp = 0; pp < 4; ++pp) {
        float va = wbuf[slot][0] * bf2f(g1[slot][2 * pp])     + wbuf[slot][1] * bf2f(g2[slot][2 * pp]) +
                   wbuf[slot][2] * bf2f(g3[slot][2 * pp])     + wbuf[slot][3] * bf2f(g4[slot][2 * pp]);
        float vb = wbuf[slot][0] * bf2f(g1[slot][2 * pp + 1]) + wbuf[slot][1] * bf2f(g2[slot][2 * pp + 1]) +
                   wbuf[slot][2] * bf2f(g3[slot][2 * pp + 1]) + wbuf[slot][3] * bf2f(g4[slot][2 * pp + 1]);
        unsigned ua = __float_as_uint(va) + 0x8000u;
        unsigned ub = __float_as_uint(vb) + 0x8000u;
        rs[pp] = __builtin_amdgcn_perm(ub, ua, 0x07060302u);
      }
      *(uint4v*)&Ab[buf][srow * 128 + half * 64 + wchA] = rs;
    };

    // prologue: gathers for sub-steps 0 and 1 (same tap, quarters 0/1)
    loadom(0);
    params(0);
    loadom(1);
    issueA(0, ic<0>{});
    issueA(1, ic<1>{});

    // pphase(p), p = 0..17: write both halves of buf p&1; prefetch ks = 2p+2, 2p+3
    auto pphase = [&](int p, auto bufc) {
      blend(ic<0>{}, ic<0>{}, bufc);              // ks = 2p  -> half 0
      {
        int ksn = 2 * p + 2;
        if (ksn < 36) {
          if ((ksn & 3) == 0) {
            int kk = ksn >> 2;
            params(kk);
            loadom(kk < 8 ? kk + 1 : 8);
          }
          issueA(ksn, ic<0>{});
        }
      }
      blend(ic<1>{}, ic<1>{}, bufc);              // ks = 2p+1 -> half 1
      {
        int ksn = 2 * p + 3;                      // never ≡0 mod 4: no params
        if (ksn < 36) issueA(ksn, ic<1>{});
      }
      LGKM0_BAR();
    };
    for (int pp = 0; pp < 9; ++pp) {
      pphase(2 * pp,     ic<0>{});
      pphase(2 * pp + 1, ic<1>{});
    }
    LGKM0_BAR();                 // 19th barrier (idle while consumers eat phase 17)
  }
}

extern "C" void kernel_launch(void* const* d_in, const int* in_sizes, int n_in,
                              void* d_out, int out_size, void* d_ws, size_t ws_size,
                              hipStream_t stream) {
  const float* x     = (const float*)d_in[0];
  const float* w_off = (const float*)d_in[1];
  const float* b_off = (const float*)d_in[2];
  const float* dcn_w = (const float*)d_in[3];
  float* out = (float*)d_out;
  char* ws = (char*)d_ws;
  unsigned short* xbf   = (unsigned short*)(ws + XBF_OFF);
  unsigned short* wrep  = (unsigned short*)(ws + WREP_OFF);
  unsigned short* wmain = (unsigned short*)(ws + WMAIN_OFF);
  float*          om    = (float*)(ws + OM_OFF);

  k_pre<<<2048 + 288, 256, 0, stream>>>(x, w_off, dcn_w, xbf, wrep, wmain);
  k_offconv<<<256, 1024, 0, stream>>>(xbf, wrep, b_off, om);
  k_gemm_fused<<<512, 512, 0, stream>>>(xbf, om, wmain, out);
}

// Round 11
// 115.692 us; speedup vs baseline: 1.0244x; 1.0244x over previous
//
#include <hip/hip_runtime.h>
#include <type_traits>

// DCNv2 forward, MI355X (gfx950).  v13: v11 gemm/offconv (verified best) +
// coalesced k_pre rewrite.
//  v12 post-mortem: 2-blocks/CU gemm REGRESSED (118.5 vs 114.0) - likely VGPR
//  over 128 at 512thr/4-per-EU (acc 32 + bfr 64 + addr) -> spill or lost
//  co-residency. gemm reverted to v11 VERBATIM (34 us, twice-verified).
//  v13's one change: k_pre transpose. Old: block owns 32 channels -> 64 B
//  contiguity, scalar ushort stores, 128 B/wave-instr. New: block = one
//  spatial row (n,y), all 256 channels; write phase: 32 lanes cover one full
//  512-B channel row with uint4 stores = 1 KB/wave-instr (G13). Reads stay
//  256-B coalesced; bf16 pairs staged in LDS tile[64][132] dwords (stride 132:
//  528 B = 33*16 -> b128-aligned reads; bounded 4-8-way bank conflicts on few
//  LDS ops - second-order vs the 8x global-store win). Weight repack folded
//  in as 144 two-oc blocks (pairs never straddle wrep/wmain boundary at 32,
//  so no divergent barriers; write logic byte-identical).
//  wmain stays in MFMA B-fragment order:
//  wmain[(k>>5)*8192 + (oc>>4)*512 + ((k>>3)&3)*128 + (oc&15)*8 + (k&7)]

typedef __bf16 bf16x8 __attribute__((ext_vector_type(8)));
typedef float  f32x4  __attribute__((ext_vector_type(4)));
typedef unsigned short ushort8 __attribute__((ext_vector_type(8)));
typedef unsigned int   uint4v  __attribute__((ext_vector_type(4)));

#define XBF_OFF   0u            // 4*4096*256*2  = 8,388,608
#define WREP_OFF  8388608u      // 32*2304*2     =   147,456
#define WMAIN_OFF 8536064u      // 256*2304*2    = 1,179,648
#define OM_OFF    9715712u      // 16384*32*4    = 2,097,152

// wait lgkmcnt(0) only (vmcnt=no wait), then barrier.
#define LGKM0_BAR() do { __builtin_amdgcn_s_waitcnt(0xC07F); __builtin_amdgcn_s_barrier(); } while (0)

template <int N> using ic = std::integral_constant<int, N>;

__device__ __forceinline__ unsigned short f2bf(float f) {
  unsigned int u = __float_as_uint(f);
  u += 0x7fffu + ((u >> 16) & 1u);
  return (unsigned short)(u >> 16);
}
__device__ __forceinline__ float bf2f(unsigned short h) {
  return __uint_as_float(((unsigned int)h) << 16);
}

// ---------------- transpose (coalesced stores) + weight repack ---------------
// Blocks 0..255: transpose role, one (n, y) row: 64 x-positions x 256 ch.
// Blocks 256..399: repack role, two output channels per block (sub-halves).
__global__ __launch_bounds__(512) void k_pre(const float* __restrict__ x,
                                             const float* __restrict__ w_off,
                                             const float* __restrict__ dcn_w,
                                             unsigned short* __restrict__ xbf,
                                             unsigned short* __restrict__ wrep,
                                             unsigned short* __restrict__ wmain) {
  __shared__ unsigned int tile2[64 * 132];   // [xx][c2] bf16-pairs, 33.8 KB
  __shared__ unsigned short lsh2[2][2304];
  int b = blockIdx.x;
  int t = threadIdx.x;
  if (b < 256) {                // transpose role
    int n  = b >> 6;
    int xb = b & 63;            // y coordinate
    // read: 4 iters, two float4 per thread (channels 2*c2, 2*c2+1)
#pragma unroll
    for (int j = 0; j < 4; ++j) {
      int c2  = j * 32 + (t >> 4);          // 0..127
      int xx0 = (t & 15) * 4;
      const float* pa = x + (((size_t)(n * 256 + 2 * c2)) << 12) + xb * 64 + xx0;
      f32x4 va = *(const f32x4*)pa;
      f32x4 vb = *(const f32x4*)(pa + 4096);
#pragma unroll
      for (int i = 0; i < 4; ++i)
        tile2[(xx0 + i) * 132 + c2] =
            (unsigned int)f2bf(va[i]) | ((unsigned int)f2bf(vb[i]) << 16);
    }
    __syncthreads();
    // write: 4 iters, uint4 per thread; 32 lanes = one full 512B channel row
#pragma unroll
    for (int k = 0; k < 4; ++k) {
      int xx = (t >> 5) + k * 16;           // 0..63
      int c8 = t & 31;                      // 16B chunk within the row
      uint4v d = *(const uint4v*)&tile2[xx * 132 + c8 * 4];
      *(uint4v*)&xbf[(((size_t)(n << 12)) + xb * 64 + xx) * 256 + c8 * 8] = d;
    }
  } else {                      // repack role: two oc per block
    int sub = t >> 8;           // 0/1 half (whole waves)
    int tt  = t & 255;
    int ocp = (b - 256) * 2 + sub;          // 0..287; pairs never straddle 32
    if (ocp < 32) {             // offset-conv weights (plain layout)
      int oc = ocp;
      bool zero = (oc >= 27);
      const float* base = w_off + (size_t)(zero ? 0 : oc) * 2304;
#pragma unroll
      for (int j = 0; j < 9; ++j)
        lsh2[sub][j * 256 + tt] = zero ? (unsigned short)0 : f2bf(base[tt * 9 + j]);
      __syncthreads();
#pragma unroll
      for (int j = 0; j < 9; ++j)
        wrep[oc * 2304 + j * 256 + tt] = lsh2[sub][j * 256 + tt];
    } else {                    // main weights: MFMA B-fragment order
      int oc = ocp - 32;
      const float* base = dcn_w + (size_t)oc * 2304;
      int oco = ((oc >> 4) << 9) + (oc & 15) * 8;
#pragma unroll
      for (int j = 0; j < 9; ++j) {
        int k = j * 256 + tt;   // logical K index: tap-major, channel-minor
        wmain[((k >> 5) << 13) + oco + (((k >> 3) & 3) << 7) + (k & 7)] =
            f2bf(base[tt * 9 + j]);
      }
    }
  }
}

// ---------------- offset-field conv: K-split-4, double-buffered, 1 bar/step --
__global__ __launch_bounds__(1024) void k_offconv(const unsigned short* __restrict__ xbf,
                                                  const unsigned short* __restrict__ wrep,
                                                  const float* __restrict__ bias,
                                                  float* __restrict__ om) {
  __shared__ __align__(16) unsigned short SHa[4][2][64 * 64];   // 64 KB
  __shared__ __align__(16) unsigned short SHb[4][2][32 * 64];   // 32 KB
  int t = threadIdx.x;
  int wave = t >> 6, lane = t & 63;
  int grp = wave >> 2, wv = wave & 3;
  int tg = t & 255;
  int bm = ((blockIdx.x & 7) << 5) + (blockIdx.x >> 3);   // XCD swizzle
  int n = bm >> 6, oy = bm & 63;

  unsigned short (*As)[64 * 64] = SHa[grp];
  unsigned short (*Bs)[32 * 64] = SHb[grp];

  int arow = tg >> 2, acc4 = tg & 3;
  int brow = tg >> 3, bch = tg & 7;

  f32x4 acc0 = {0.f, 0.f, 0.f, 0.f};
  f32x4 acc1 = {0.f, 0.f, 0.f, 0.f};

  ushort8 av[2][2]; ushort8 bv[2];
  auto prefetch = [&](int ktg, auto slotc) {
    constexpr int slot = decltype(slotc)::value;
    int kk = ktg >> 2;
    int c0 = (ktg & 3) * 64;
    int dy = kk / 3 - 1, dx = kk % 3 - 1;
    int yy = oy + dy, xxg = arow + dx;
    bool ok = ((unsigned)yy < 64u) && ((unsigned)xxg < 64u);
    const unsigned short* p = xbf + (size_t)(((n * 64 + yy) * 64 + xxg) * 256 + c0 + acc4 * 16);
#pragma unroll
    for (int g = 0; g < 2; ++g)
      av[slot][g] = ok ? *(const ushort8*)(p + g * 8) : (ushort8){0,0,0,0,0,0,0,0};
    bv[slot] = *(const ushort8*)(wrep + (size_t)brow * 2304 + ktg * 64 + bch * 8);
  };

  int k0 = grp * 9;
  prefetch(k0, ic<0>{});
  prefetch(k0 + 1, ic<1>{});
  int mr = lane & 15, q = lane >> 4;

  // step kt: write LDS buf kt&1, prefetch kt+2, ONE barrier, MFMA from buf kt&1.
  auto step = [&](int kt, auto slotc) {
    constexpr int slot = decltype(slotc)::value;
#pragma unroll
    for (int g = 0; g < 2; ++g) {
      int ch = (acc4 * 2 + g) ^ (arow & 7);
      *(ushort8*)&As[slot][arow * 64 + ch * 8] = av[slot][g];
    }
    { int ch = bch ^ (brow & 7);
      *(ushort8*)&Bs[slot][brow * 64 + ch * 8] = bv[slot]; }
    if (kt + 2 < 9) prefetch(k0 + kt + 2, slotc);
    LGKM0_BAR();
#pragma unroll
    for (int kh = 0; kh < 2; ++kh) {
      int coff = ((q + kh * 4) ^ (mr & 7)) * 8;
      bf16x8 a  = *(const bf16x8*)&As[slot][(wv * 16 + mr) * 64 + coff];
      bf16x8 b0 = *(const bf16x8*)&Bs[slot][mr * 64 + coff];
      bf16x8 b1 = *(const bf16x8*)&Bs[slot][(16 + mr) * 64 + coff];
      acc0 = __builtin_amdgcn_mfma_f32_16x16x32_bf16(a, b0, acc0, 0, 0, 0);
      acc1 = __builtin_amdgcn_mfma_f32_16x16x32_bf16(a, b1, acc1, 0, 0, 0);
    }
  };
  for (int kp = 0; kp < 4; ++kp) {
    step(2 * kp, ic<0>{});
    step(2 * kp + 1, ic<1>{});
  }
  step(8, ic<0>{});

  float* scratch = (float*)&SHa[0][0][0];
  __syncthreads();
  if (grp > 0) {
#pragma unroll
    for (int nt = 0; nt < 2; ++nt) {
      f32x4 a = nt ? acc1 : acc0;
#pragma unroll
      for (int rg = 0; rg < 4; ++rg)
        scratch[(grp - 1) * 2048 + (wv * 16 + q * 4 + rg) * 32 + nt * 16 + mr] = a[rg];
    }
  }
  __syncthreads();
  if (grp == 0) {
    int r0 = bm * 64;
#pragma unroll
    for (int nt = 0; nt < 2; ++nt) {
      f32x4 a = nt ? acc1 : acc0;
      int oc = nt * 16 + mr;
      float bvl = (oc < 27) ? bias[oc] : 0.f;
#pragma unroll
      for (int rg = 0; rg < 4; ++rg) {
        int pl = wv * 16 + q * 4 + rg;
        float v = a[rg] + bvl + scratch[pl * 32 + oc] +
                  scratch[2048 + pl * 32 + oc] + scratch[4096 + pl * 32 + oc];
        if (oc >= 18 && oc < 27) v = 1.f / (1.f + __expf(-v));
        om[(r0 + pl) * 32 + oc] = v;
      }
    }
  }
}

// ---------------- fused deformable-im2col GEMM (v9/v11 VERBATIM, verified) ---
// Role-split lockstep, B in consumer registers, BK=128 phases (19 barriers).
// 1024 thr, 16 waves, LDS: Ab[2][64*128] = 32 KB.
__global__ __launch_bounds__(1024, 4) void k_gemm_fused(const unsigned short* __restrict__ xbf,
                                                        const float* __restrict__ om,
                                                        const unsigned short* __restrict__ wB,
                                                        float* __restrict__ out) {
  __shared__ __align__(16) unsigned short Ab[2][64 * 128];   // 32 KB
  int t = threadIdx.x;
  int wave = t >> 6, lane = t & 63;
  int bmx = ((blockIdx.x & 7) << 5) + (blockIdx.x >> 3);     // XCD swizzle
  int r0 = bmx * 64;

  if (wave < 8) {
    // ============ consumers: waves 0..7, 64 rows x 32 oc each ===============
    int mr = lane & 15, q = lane >> 4;
    const unsigned short* Bg = wB + wave * 1024 + lane * 8;  // frag base (oc blk)
    f32x4 acc[4][2];
#pragma unroll
    for (int mt = 0; mt < 4; ++mt)
#pragma unroll
      for (int nt = 0; nt < 2; ++nt) acc[mt][nt] = (f32x4){0.f, 0.f, 0.f, 0.f};

    bf16x8 bfr[2][4];            // [slot = ks&1][kh*2+nt], ks = 64-K sub-step

    auto issueB = [&](int ks, auto slotc) {      // B(ks) -> slot
      constexpr int slot = decltype(slotc)::value;
#pragma unroll
      for (int kh = 0; kh < 2; ++kh)
#pragma unroll
        for (int nt = 0; nt < 2; ++nt)
          bfr[slot][kh * 2 + nt] =
              *(const bf16x8*)(Bg + (size_t)(ks * 2 + kh) * 8192 + nt * 512);
    };
    // MFMA for sub-step ks: half = ks&1 (compile-time), B slot = ks&1, buf = (ks>>1)&1
    auto mfma64 = [&](auto halfc, auto bufc) {
      constexpr int half = decltype(halfc)::value;
      constexpr int buf  = decltype(bufc)::value;
      __builtin_amdgcn_s_setprio(1);
#pragma unroll
      for (int kh = 0; kh < 2; ++kh) {
        int coff = half * 64 + ((q + kh * 4) ^ (mr & 7)) * 8;
        bf16x8 af[4];
#pragma unroll
        for (int mt = 0; mt < 4; ++mt)
          af[mt] = *(const bf16x8*)&Ab[buf][(mt * 16 + mr) * 128 + coff];
#pragma unroll
        for (int mt = 0; mt < 4; ++mt)
#pragma unroll
          for (int nt = 0; nt < 2; ++nt)
            acc[mt][nt] = __builtin_amdgcn_mfma_f32_16x16x32_bf16(
                af[mt], bfr[half][kh * 2 + nt], acc[mt][nt], 0, 0, 0);
      }
      __builtin_amdgcn_s_setprio(0);
    };

    // prologue: phase 0 (producers fill buf0); issue B(0).
    issueB(0, ic<0>{});
    LGKM0_BAR();
    // phases p = 1..18: consume buf (p-1)&1 (sub-steps 2p-2, 2p-1)
    auto cphase = [&](int p, auto bufc) {
      issueB(2 * p - 1, ic<1>{});            // used this phase, 2nd sub
      mfma64(ic<0>{}, bufc);                 // MFMA(2p-2): half0, slot0
      if (2 * p < 36) issueB(2 * p, ic<0>{}); // for next phase's 1st sub
      mfma64(ic<1>{}, bufc);                 // MFMA(2p-1): half1, slot1
      LGKM0_BAR();                           // lgkm-only: B loads stay in flight
    };
    for (int pp = 0; pp < 9; ++pp) {
      cphase(2 * pp + 1, ic<0>{});
      cphase(2 * pp + 2, ic<1>{});
    }

    // epilogue: direct stores
#pragma unroll
    for (int mt = 0; mt < 4; ++mt)
#pragma unroll
      for (int nt = 0; nt < 2; ++nt) {
        int p = r0 + mt * 16 + q * 4;
        int o = wave * 32 + nt * 16 + mr;
        int nn = p >> 12, pyx = p & 4095;
        *(f32x4*)(out + ((size_t)(nn * 256 + o) << 12) + pyx) = acc[mt][nt];
      }
  } else {
    // ============ producers: waves 8..15 (A only) ===========================
    int pt = t - 512;                    // 0..511
    int srow = pt >> 3, sch = (pt & 7) * 8;   // 64 rows x 8 ch-chunks of 8
    int r = r0 + srow;
    int n = r >> 12, yx = r & 4095, oy = yx >> 6, ox = yx & 63;
    const unsigned short* xb = xbf + (size_t)n * (4096 * 256);
    const float* omr = om + (size_t)r * 32;
    int wchA = (((pt & 7) ^ (srow & 7)) << 3);

    float pv_y, pv_x, pv_m;
    float cw1, cw2, cw3, cw4;
    int a1, a2, a3, a4;
    float wbuf[2][4];
    ushort8 g1[2], g2[2], g3[2], g4[2];

    auto loadom = [&](int kk) {
      pv_y = omr[2 * kk]; pv_x = omr[2 * kk + 1]; pv_m = omr[18 + kk];
    };
    auto params = [&](int kk) {
      float py = (float)(oy + kk / 3) + pv_y;
      float px = (float)(ox + kk % 3) + pv_x;
      float m = pv_m;
      py = fminf(fmaxf(py, 0.f), 65.f);
      px = fminf(fmaxf(px, 0.f), 65.f);
      float fy = floorf(py), fx = floorf(px);
      float ly = py - fy, lx = px - fx;
      float hy = 1.f - ly, hx = 1.f - lx;
      int iy = (int)fy, ix = (int)fx;
      bool yv0 = (iy >= 1) && (iy <= 64);
      bool yv1 = (iy <= 63);
      bool xv0 = (ix >= 1) && (ix <= 64);
      bool xv1 = (ix <= 63);
      int y0 = min(max(iy - 1, 0), 63);
      int y1 = min(iy, 63);
      int x0 = min(max(ix - 1, 0), 63);
      int x1 = min(ix, 63);
      cw1 = (yv0 && xv0) ? hy * hx * m : 0.f;
      cw2 = (yv0 && xv1) ? hy * lx * m : 0.f;
      cw3 = (yv1 && xv0) ? ly * hx * m : 0.f;
      cw4 = (yv1 && xv1) ? ly * lx * m : 0.f;
      a1 = ((y0 << 6) + x0) * 256;
      a2 = ((y0 << 6) + x1) * 256;
      a3 = ((y1 << 6) + x0) * 256;
      a4 = ((y1 << 6) + x1) * 256;
    };

    auto issueA = [&](int ktg, auto slotc) {
      constexpr int slot = decltype(slotc)::value;
      wbuf[slot][0] = cw1; wbuf[slot][1] = cw2; wbuf[slot][2] = cw3; wbuf[slot][3] = cw4;
      int c = (ktg & 3) * 64 + sch;
      g1[slot] = *(const ushort8*)(xb + a1 + c);
      g2[slot] = *(const ushort8*)(xb + a2 + c);
      g3[slot] = *(const ushort8*)(xb + a3 + c);
      g4[slot] = *(const ushort8*)(xb + a4 + c);
    };
    // blend sub-step from slot, write half of buf
    auto blend = [&](auto slotc, auto halfc, auto bufc) {
      constexpr int slot = decltype(slotc)::value;
      constexpr int half = decltype(halfc)::value;
      constexpr int buf  = decltype(bufc)::value;
      uint4v rs;
#pragma unroll
      for (int pp = 0; pp < 4; ++pp) {
        float va = wbuf[slot][0] * bf2f(g1[slot][2 * pp])     + wbuf[slot][1] * bf2f(g2[slot][2 * pp]) +
                   wbuf[slot][2] * bf2f(g3[slot][2 * pp])     + wbuf[slot][3] * bf2f(g4[slot][2 * pp]);
        float vb = wbuf[slot][0] * bf2f(g1[slot][2 * pp + 1]) + wbuf[slot][1] * bf2f(g2[slot][2 * pp + 1]) +
                   wbuf[slot][2] * bf2f(g3[slot][2 * pp + 1]) + wbuf[slot][3] * bf2f(g4[slot][2 * pp + 1]);
        unsigned ua = __float_as_uint(va) + 0x8000u;
        unsigned ub = __float_as_uint(vb) + 0x8000u;
        rs[pp] = __builtin_amdgcn_perm(ub, ua, 0x07060302u);
      }
      *(uint4v*)&Ab[buf][srow * 128 + half * 64 + wchA] = rs;
    };

    // prologue: gathers for sub-steps 0 and 1 (same tap, quarters 0/1)
    loadom(0);
    params(0);
    loadom(1);
    issueA(0, ic<0>{});
    issueA(1, ic<1>{});

    // pphase(p), p = 0..17: write both halves of buf p&1; prefetch ks = 2p+2, 2p+3
    auto pphase = [&](int p, auto bufc) {
      blend(ic<0>{}, ic<0>{}, bufc);              // ks = 2p  -> half 0
      {
        int ksn = 2 * p + 2;
        if (ksn < 36) {
          if ((ksn & 3) == 0) {
            int kk = ksn >> 2;
            params(kk);
            loadom(kk < 8 ? kk + 1 : 8);
          }
          issueA(ksn, ic<0>{});
        }
      }
      blend(ic<1>{}, ic<1>{}, bufc);              // ks = 2p+1 -> half 1
      {
        int ksn = 2 * p + 3;                      // never ≡0 mod 4: no params
        if (ksn < 36) issueA(ksn, ic<1>{});
      }
      LGKM0_BAR();
    };
    for (int pp = 0; pp < 9; ++pp) {
      pphase(2 * pp,     ic<0>{});
      pphase(2 * pp + 1, ic<1>{});
    }
    LGKM0_BAR();                 // 19th barrier (idle while consumers eat phase 17)
  }
}

extern "C" void kernel_launch(void* const* d_in, const int* in_sizes, int n_in,
                              void* d_out, int out_size, void* d_ws, size_t ws_size,
                              hipStream_t stream) {
  const float* x     = (const float*)d_in[0];
  const float* w_off = (const float*)d_in[1];
  const float* b_off = (const float*)d_in[2];
  const float* dcn_w = (const float*)d_in[3];
  float* out = (float*)d_out;
  char* ws = (char*)d_ws;
  unsigned short* xbf   = (unsigned short*)(ws + XBF_OFF);
  unsigned short* wrep  = (unsigned short*)(ws + WREP_OFF);
  unsigned short* wmain = (unsigned short*)(ws + WMAIN_OFF);
  float*          om    = (float*)(ws + OM_OFF);

  k_pre<<<256 + 144, 512, 0, stream>>>(x, w_off, dcn_w, xbf, wrep, wmain);
  k_offconv<<<256, 1024, 0, stream>>>(xbf, wrep, b_off, om);
  k_gemm_fused<<<256, 1024, 0, stream>>>(xbf, om, wmain, out);
}

// Round 12
// 111.141 us; speedup vs baseline: 1.0663x; 1.0409x over previous
//
#include <hip/hip_runtime.h>
#include <type_traits>

// DCNv2 forward, MI355X (gfx950).  v14: fuse offconv into the gemm kernel.
//  v13 post-mortem: coalesced-k_pre rewrite regressed/neutral (115.7 vs 114.0)
//  -> k_pre reverted to v11 VERBATIM. gemm + offconv loops are at their
//  structure-level optima (v9/v11 verified; fewer barriers helps, more
//  barrier groups and BK=256 both convicted).
//  v14's one change: k_offconv's only consumer is the gemm, and the
//  dependency is BLOCK-LOCAL (offconv block bm produces om rows bm*64..+63;
//  gemm block with the SAME swizzle consumes exactly those rows). Fusion:
//   phase A = v11 offconv verbatim, group-0 writes om_lds[64][32] (8 KB LDS)
//             instead of global om;
//   one uniform __syncthreads() transition;
//   phase B = v11 gemm verbatim, omr -> om_lds (LDS reads, lgkm-covered).
//  Removes: one kernel launch + inter-kernel drain + om's 2MB write + 2MB
//  read. LDS aliasing: offconv's 96 KB dead after transition; Ab (32 KB)
//  overlays it; om_lds separate; peak 104 KB < 160 KB (1 block/CU as before).
//  wmain stays in MFMA B-fragment order:
//  wmain[(k>>5)*8192 + (oc>>4)*512 + ((k>>3)&3)*128 + (oc&15)*8 + (k&7)]

typedef __bf16 bf16x8 __attribute__((ext_vector_type(8)));
typedef float  f32x4  __attribute__((ext_vector_type(4)));
typedef unsigned short ushort8 __attribute__((ext_vector_type(8)));
typedef unsigned int   uint4v  __attribute__((ext_vector_type(4)));

#define XBF_OFF   0u            // 4*4096*256*2  = 8,388,608
#define WREP_OFF  8388608u      // 32*2304*2     =   147,456
#define WMAIN_OFF 8536064u      // 256*2304*2    = 1,179,648

// wait lgkmcnt(0) only (vmcnt=no wait), then barrier.
#define LGKM0_BAR() do { __builtin_amdgcn_s_waitcnt(0xC07F); __builtin_amdgcn_s_barrier(); } while (0)

template <int N> using ic = std::integral_constant<int, N>;

__device__ __forceinline__ unsigned short f2bf(float f) {
  unsigned int u = __float_as_uint(f);
  u += 0x7fffu + ((u >> 16) & 1u);
  return (unsigned short)(u >> 16);
}
__device__ __forceinline__ float bf2f(unsigned short h) {
  return __uint_as_float(((unsigned int)h) << 16);
}

// ---------------- merged transpose + weight repack (v11 VERBATIM) -----------
__global__ __launch_bounds__(256) void k_pre(const float* __restrict__ x,
                                             const float* __restrict__ w_off,
                                             const float* __restrict__ dcn_w,
                                             unsigned short* __restrict__ xbf,
                                             unsigned short* __restrict__ wrep,
                                             unsigned short* __restrict__ wmain) {
  __shared__ float tile[32][65];
  __shared__ unsigned short lsh[2304];
  int b = blockIdx.x;
  int t = threadIdx.x;
  if (b < 2048) {               // transpose role
    int n  = b >> 9;
    int cb = (b >> 6) & 7;
    int xb = b & 63;
    int xx  = t & 63;
    int cc0 = t >> 6;
#pragma unroll
    for (int j = 0; j < 8; ++j) {
      int cc = cc0 + j * 4;
      tile[cc][xx] = x[((size_t)(n * 256 + cb * 32 + cc) << 12) + xb * 64 + xx];
    }
    __syncthreads();
    int ccw = t & 31;
    int xw0 = t >> 5;
#pragma unroll
    for (int j = 0; j < 8; ++j) {
      int xw = xw0 + j * 8;
      xbf[((size_t)((n << 12) + xb * 64 + xw)) * 256 + cb * 32 + ccw] = f2bf(tile[ccw][xw]);
    }
  } else {                      // repack role: one block per output channel
    int ocb = b - 2048;
    if (ocb < 32) {             // offset-conv weights: layout unchanged
      int oc = ocb;
      if (oc >= 27) {
#pragma unroll
        for (int j = 0; j < 9; ++j) wrep[oc * 2304 + j * 256 + t] = 0;
        return;
      }
      const float* base = w_off + (size_t)oc * 2304;
#pragma unroll
      for (int j = 0; j < 9; ++j) lsh[j * 256 + t] = f2bf(base[t * 9 + j]);
      __syncthreads();
#pragma unroll
      for (int j = 0; j < 9; ++j) wrep[oc * 2304 + j * 256 + t] = lsh[j * 256 + t];
    } else {                    // main weights: MFMA B-fragment order
      int oc = ocb - 32;
      const float* base = dcn_w + (size_t)oc * 2304;
      int oco = ((oc >> 4) << 9) + (oc & 15) * 8;
#pragma unroll
      for (int j = 0; j < 9; ++j) {
        int k = j * 256 + t;    // logical K index: tap-major, channel-minor
        wmain[((k >> 5) << 13) + oco + (((k >> 3) & 3) << 7) + (k & 7)] =
            f2bf(base[t * 9 + j]);
      }
    }
  }
}

// ---------------- fused offconv + deformable-im2col GEMM v14 -----------------
// Phase A: v11 offconv (K-split-4, double-buffered, 1 bar/step), om -> LDS.
// Phase B: v11 gemm (role-split, B in consumer regs, BK=128, 19 barriers).
// LDS: smem 96 KB (offconv SHa/SHb, reused as Ab 32 KB) + om_lds 8 KB.
__global__ __launch_bounds__(1024, 4) void k_gemm_fused(const unsigned short* __restrict__ xbf,
                                                        const unsigned short* __restrict__ wrep,
                                                        const float* __restrict__ bias,
                                                        const unsigned short* __restrict__ wB,
                                                        float* __restrict__ out) {
  __shared__ __align__(16) unsigned char smem[98304];   // 96 KB aliased region
  __shared__ __align__(16) float om_lds[64 * 32];       // 8 KB, persists A->B
  int t = threadIdx.x;
  int wave = t >> 6, lane = t & 63;
  int bm = ((blockIdx.x & 7) << 5) + (blockIdx.x >> 3);  // XCD swizzle (shared)
  int n = bm >> 6, oy = bm & 63;
  int mr = lane & 15, q = lane >> 4;

  // ==================== phase A: offset-field conv ==========================
  {
    auto SHa = reinterpret_cast<unsigned short (*)[2][64 * 64]>(smem);           // [4][2][4096]
    auto SHb = reinterpret_cast<unsigned short (*)[2][32 * 64]>(smem + 65536);   // [4][2][2048]
    int grp = wave >> 2, wv = wave & 3;
    int tg = t & 255;

    unsigned short (*As)[64 * 64] = SHa[grp];
    unsigned short (*Bs)[32 * 64] = SHb[grp];

    int arow = tg >> 2, acc4 = tg & 3;
    int brow = tg >> 3, bch = tg & 7;

    f32x4 acc0 = {0.f, 0.f, 0.f, 0.f};
    f32x4 acc1 = {0.f, 0.f, 0.f, 0.f};

    ushort8 av[2][2]; ushort8 bv[2];
    auto prefetch = [&](int ktg, auto slotc) {
      constexpr int slot = decltype(slotc)::value;
      int kk = ktg >> 2;
      int c0 = (ktg & 3) * 64;
      int dy = kk / 3 - 1, dx = kk % 3 - 1;
      int yy = oy + dy, xxg = arow + dx;
      bool ok = ((unsigned)yy < 64u) && ((unsigned)xxg < 64u);
      const unsigned short* p = xbf + (size_t)(((n * 64 + yy) * 64 + xxg) * 256 + c0 + acc4 * 16);
#pragma unroll
      for (int g = 0; g < 2; ++g)
        av[slot][g] = ok ? *(const ushort8*)(p + g * 8) : (ushort8){0,0,0,0,0,0,0,0};
      bv[slot] = *(const ushort8*)(wrep + (size_t)brow * 2304 + ktg * 64 + bch * 8);
    };

    int k0 = grp * 9;
    prefetch(k0, ic<0>{});
    prefetch(k0 + 1, ic<1>{});

    auto step = [&](int kt, auto slotc) {
      constexpr int slot = decltype(slotc)::value;
#pragma unroll
      for (int g = 0; g < 2; ++g) {
        int ch = (acc4 * 2 + g) ^ (arow & 7);
        *(ushort8*)&As[slot][arow * 64 + ch * 8] = av[slot][g];
      }
      { int ch = bch ^ (brow & 7);
        *(ushort8*)&Bs[slot][brow * 64 + ch * 8] = bv[slot]; }
      if (kt + 2 < 9) prefetch(k0 + kt + 2, slotc);
      LGKM0_BAR();
#pragma unroll
      for (int kh = 0; kh < 2; ++kh) {
        int coff = ((q + kh * 4) ^ (mr & 7)) * 8;
        bf16x8 a  = *(const bf16x8*)&As[slot][(wv * 16 + mr) * 64 + coff];
        bf16x8 b0 = *(const bf16x8*)&Bs[slot][mr * 64 + coff];
        bf16x8 b1 = *(const bf16x8*)&Bs[slot][(16 + mr) * 64 + coff];
        acc0 = __builtin_amdgcn_mfma_f32_16x16x32_bf16(a, b0, acc0, 0, 0, 0);
        acc1 = __builtin_amdgcn_mfma_f32_16x16x32_bf16(a, b1, acc1, 0, 0, 0);
      }
    };
    for (int kp = 0; kp < 4; ++kp) {
      step(2 * kp, ic<0>{});
      step(2 * kp + 1, ic<1>{});
    }
    step(8, ic<0>{});

    float* scratch = (float*)smem;
    __syncthreads();
    if (grp > 0) {
#pragma unroll
      for (int nt = 0; nt < 2; ++nt) {
        f32x4 a = nt ? acc1 : acc0;
#pragma unroll
        for (int rg = 0; rg < 4; ++rg)
          scratch[(grp - 1) * 2048 + (wv * 16 + q * 4 + rg) * 32 + nt * 16 + mr] = a[rg];
      }
    }
    __syncthreads();
    if (grp == 0) {
#pragma unroll
      for (int nt = 0; nt < 2; ++nt) {
        f32x4 a = nt ? acc1 : acc0;
        int oc = nt * 16 + mr;
        float bvl = (oc < 27) ? bias[oc] : 0.f;
#pragma unroll
        for (int rg = 0; rg < 4; ++rg) {
          int pl = wv * 16 + q * 4 + rg;
          float v = a[rg] + bvl + scratch[pl * 32 + oc] +
                    scratch[2048 + pl * 32 + oc] + scratch[4096 + pl * 32 + oc];
          if (oc >= 18 && oc < 27) v = 1.f / (1.f + __expf(-v));
          om_lds[pl * 32 + oc] = v;
        }
      }
    }
  }
  __syncthreads();   // om_lds visible to all; offconv smem region dead

  // ==================== phase B: fused deformable-im2col GEMM ===============
  auto Ab = reinterpret_cast<unsigned short (*)[64 * 128]>(smem);   // [2][8192]
  int r0 = bm * 64;

  if (wave < 8) {
    // ============ consumers: waves 0..7, 64 rows x 32 oc each ===============
    const unsigned short* Bg = wB + wave * 1024 + lane * 8;  // frag base (oc blk)
    f32x4 acc[4][2];
#pragma unroll
    for (int mt = 0; mt < 4; ++mt)
#pragma unroll
      for (int nt = 0; nt < 2; ++nt) acc[mt][nt] = (f32x4){0.f, 0.f, 0.f, 0.f};

    bf16x8 bfr[2][4];            // [slot = ks&1][kh*2+nt], ks = 64-K sub-step

    auto issueB = [&](int ks, auto slotc) {      // B(ks) -> slot
      constexpr int slot = decltype(slotc)::value;
#pragma unroll
      for (int kh = 0; kh < 2; ++kh)
#pragma unroll
        for (int nt = 0; nt < 2; ++nt)
          bfr[slot][kh * 2 + nt] =
              *(const bf16x8*)(Bg + (size_t)(ks * 2 + kh) * 8192 + nt * 512);
    };
    // MFMA for sub-step ks: half = ks&1 (compile-time), B slot = ks&1, buf = (ks>>1)&1
    auto mfma64 = [&](auto halfc, auto bufc) {
      constexpr int half = decltype(halfc)::value;
      constexpr int buf  = decltype(bufc)::value;
      __builtin_amdgcn_s_setprio(1);
#pragma unroll
      for (int kh = 0; kh < 2; ++kh) {
        int coff = half * 64 + ((q + kh * 4) ^ (mr & 7)) * 8;
        bf16x8 af[4];
#pragma unroll
        for (int mt = 0; mt < 4; ++mt)
          af[mt] = *(const bf16x8*)&Ab[buf][(mt * 16 + mr) * 128 + coff];
#pragma unroll
        for (int mt = 0; mt < 4; ++mt)
#pragma unroll
          for (int nt = 0; nt < 2; ++nt)
            acc[mt][nt] = __builtin_amdgcn_mfma_f32_16x16x32_bf16(
                af[mt], bfr[half][kh * 2 + nt], acc[mt][nt], 0, 0, 0);
      }
      __builtin_amdgcn_s_setprio(0);
    };

    // prologue: phase 0 (producers fill buf0); issue B(0).
    issueB(0, ic<0>{});
    LGKM0_BAR();
    // phases p = 1..18: consume buf (p-1)&1 (sub-steps 2p-2, 2p-1)
    auto cphase = [&](int p, auto bufc) {
      issueB(2 * p - 1, ic<1>{});            // used this phase, 2nd sub
      mfma64(ic<0>{}, bufc);                 // MFMA(2p-2): half0, slot0
      if (2 * p < 36) issueB(2 * p, ic<0>{}); // for next phase's 1st sub
      mfma64(ic<1>{}, bufc);                 // MFMA(2p-1): half1, slot1
      LGKM0_BAR();                           // lgkm-only: B loads stay in flight
    };
    for (int pp = 0; pp < 9; ++pp) {
      cphase(2 * pp + 1, ic<0>{});
      cphase(2 * pp + 2, ic<1>{});
    }

    // epilogue: direct stores
#pragma unroll
    for (int mt = 0; mt < 4; ++mt)
#pragma unroll
      for (int nt = 0; nt < 2; ++nt) {
        int p = r0 + mt * 16 + q * 4;
        int o = wave * 32 + nt * 16 + mr;
        int nn = p >> 12, pyx = p & 4095;
        *(f32x4*)(out + ((size_t)(nn * 256 + o) << 12) + pyx) = acc[mt][nt];
      }
  } else {
    // ============ producers: waves 8..15 (A only) ===========================
    int pt = t - 512;                    // 0..511
    int srow = pt >> 3, sch = (pt & 7) * 8;   // 64 rows x 8 ch-chunks of 8
    int r = r0 + srow;
    int rn = r >> 12, yx = r & 4095, poy = yx >> 6, pox = yx & 63;
    const unsigned short* xb = xbf + (size_t)rn * (4096 * 256);
    const float* omr = om_lds + srow * 32;        // om from LDS (phase A)
    int wchA = (((pt & 7) ^ (srow & 7)) << 3);

    float pv_y, pv_x, pv_m;
    float cw1, cw2, cw3, cw4;
    int a1, a2, a3, a4;
    float wbuf[2][4];
    ushort8 g1[2], g2[2], g3[2], g4[2];

    auto loadom = [&](int kk) {
      pv_y = omr[2 * kk]; pv_x = omr[2 * kk + 1]; pv_m = omr[18 + kk];
    };
    auto params = [&](int kk) {
      float py = (float)(poy + kk / 3) + pv_y;
      float px = (float)(pox + kk % 3) + pv_x;
      float m = pv_m;
      py = fminf(fmaxf(py, 0.f), 65.f);
      px = fminf(fmaxf(px, 0.f), 65.f);
      float fy = floorf(py), fx = floorf(px);
      float ly = py - fy, lx = px - fx;
      float hy = 1.f - ly, hx = 1.f - lx;
      int iy = (int)fy, ix = (int)fx;
      bool yv0 = (iy >= 1) && (iy <= 64);
      bool yv1 = (iy <= 63);
      bool xv0 = (ix >= 1) && (ix <= 64);
      bool xv1 = (ix <= 63);
      int y0 = min(max(iy - 1, 0), 63);
      int y1 = min(iy, 63);
      int x0 = min(max(ix - 1, 0), 63);
      int x1 = min(ix, 63);
      cw1 = (yv0 && xv0) ? hy * hx * m : 0.f;
      cw2 = (yv0 && xv1) ? hy * lx * m : 0.f;
      cw3 = (yv1 && xv0) ? ly * hx * m : 0.f;
      cw4 = (yv1 && xv1) ? ly * lx * m : 0.f;
      a1 = ((y0 << 6) + x0) * 256;
      a2 = ((y0 << 6) + x1) * 256;
      a3 = ((y1 << 6) + x0) * 256;
      a4 = ((y1 << 6) + x1) * 256;
    };

    auto issueA = [&](int ktg, auto slotc) {
      constexpr int slot = decltype(slotc)::value;
      wbuf[slot][0] = cw1; wbuf[slot][1] = cw2; wbuf[slot][2] = cw3; wbuf[slot][3] = cw4;
      int c = (ktg & 3) * 64 + sch;
      g1[slot] = *(const ushort8*)(xb + a1 + c);
      g2[slot] = *(const ushort8*)(xb + a2 + c);
      g3[slot] = *(const ushort8*)(xb + a3 + c);
      g4[slot] = *(const ushort8*)(xb + a4 + c);
    };
    // blend sub-step from slot, write half of buf
    auto blend = [&](auto slotc, auto halfc, auto bufc) {
      constexpr int slot = decltype(slotc)::value;
      constexpr int half = decltype(halfc)::value;
      constexpr int buf  = decltype(bufc)::value;
      uint4v rs;
#pragma unroll
      for (int pp = 0; pp < 4; ++pp) {
        float va = wbuf[slot][0] * bf2f(g1[slot][2 * pp])     + wbuf[slot][1] * bf2f(g2[slot][2 * pp]) +
                   wbuf[slot][2] * bf2f(g3[slot][2 * pp])     + wbuf[slot][3] * bf2f(g4[slot][2 * pp]);
        float vb = wbuf[slot][0] * bf2f(g1[slot][2 * pp + 1]) + wbuf[slot][1] * bf2f(g2[slot][2 * pp + 1]) +
                   wbuf[slot][2] * bf2f(g3[slot][2 * pp + 1]) + wbuf[slot][3] * bf2f(g4[slot][2 * pp + 1]);
        unsigned ua = __float_as_uint(va) + 0x8000u;
        unsigned ub = __float_as_uint(vb) + 0x8000u;
        rs[pp] = __builtin_amdgcn_perm(ub, ua, 0x07060302u);
      }
      *(uint4v*)&Ab[buf][srow * 128 + half * 64 + wchA] = rs;
    };

    // prologue: gathers for sub-steps 0 and 1 (same tap, quarters 0/1)
    loadom(0);
    params(0);
    loadom(1);
    issueA(0, ic<0>{});
    issueA(1, ic<1>{});

    // pphase(p), p = 0..17: write both halves of buf p&1; prefetch ks = 2p+2, 2p+3
    auto pphase = [&](int p, auto bufc) {
      blend(ic<0>{}, ic<0>{}, bufc);              // ks = 2p  -> half 0
      {
        int ksn = 2 * p + 2;
        if (ksn < 36) {
          if ((ksn & 3) == 0) {
            int kk = ksn >> 2;
            params(kk);
            loadom(kk < 8 ? kk + 1 : 8);
          }
          issueA(ksn, ic<0>{});
        }
      }
      blend(ic<1>{}, ic<1>{}, bufc);              // ks = 2p+1 -> half 1
      {
        int ksn = 2 * p + 3;                      // never ≡0 mod 4: no params
        if (ksn < 36) issueA(ksn, ic<1>{});
      }
      LGKM0_BAR();
    };
    for (int pp = 0; pp < 9; ++pp) {
      pphase(2 * pp,     ic<0>{});
      pphase(2 * pp + 1, ic<1>{});
    }
    LGKM0_BAR();                 // 19th barrier (idle while consumers eat phase 17)
  }
}

extern "C" void kernel_launch(void* const* d_in, const int* in_sizes, int n_in,
                              void* d_out, int out_size, void* d_ws, size_t ws_size,
                              hipStream_t stream) {
  const float* x     = (const float*)d_in[0];
  const float* w_off = (const float*)d_in[1];
  const float* b_off = (const float*)d_in[2];
  const float* dcn_w = (const float*)d_in[3];
  float* out = (float*)d_out;
  char* ws = (char*)d_ws;
  unsigned short* xbf   = (unsigned short*)(ws + XBF_OFF);
  unsigned short* wrep  = (unsigned short*)(ws + WREP_OFF);
  unsigned short* wmain = (unsigned short*)(ws + WMAIN_OFF);

  k_pre<<<2048 + 288, 256, 0, stream>>>(x, w_off, dcn_w, xbf, wrep, wmain);
  k_gemm_fused<<<256, 1024, 0, stream>>>(xbf, wrep, b_off, wmain, out);
}